// Round 1
// baseline (213.045 us; speedup 1.0000x reference)
//
#include <hip/hip_runtime.h>
#include <hip/hip_bf16.h>

typedef __bf16 bf16_t;
typedef __bf16 bf16x8 __attribute__((ext_vector_type(8)));
typedef __bf16 bf16x4 __attribute__((ext_vector_type(4)));
typedef float f32x4 __attribute__((ext_vector_type(4)));
typedef unsigned int u32;

#define D_MODEL 1024
#define T_SEQ   2048
#define N_HEADS 16

__device__ __forceinline__ void gload_lds16(const void* g, void* l) {
  __builtin_amdgcn_global_load_lds((const __attribute__((address_space(1))) u32*)g,
                                   (__attribute__((address_space(3))) u32*)l, 16, 0, 0);
}

// ---------------- fused fp32->bf16 cast (x + 4 weights) ----------------
struct CastArgs { const float* src[5]; bf16_t* dst[5]; };

__global__ __launch_bounds__(256) void cast_all(CastArgs p) {
  unsigned i = (blockIdx.x * 256u + threadIdx.x) * 4u;
  int seg; unsigned off;
  if (i < 4194304u) { seg = 0; off = i; }
  else { unsigned r = i - 4194304u; seg = 1 + (int)(r >> 20); off = r & 1048575u; }
  const float4 v = *(const float4*)(p.src[seg] + off);
  bf16x4 o = { (bf16_t)v.x, (bf16_t)v.y, (bf16_t)v.z, (bf16_t)v.w };
  *(bf16x4*)(p.dst[seg] + off) = o;
}

// ---------------- 128x128 bf16 GEMM tile, C = A @ W^T ----------------
// A: [M][1024] bf16 row-major, W: [N][1024] bf16 row-major (so W^T GEMM = both row-contig)
__device__ __forceinline__ void gemm_tile_128(
    const bf16_t* __restrict__ A, const bf16_t* __restrict__ W,
    bf16_t* Als, bf16_t* Bls, int brow, int bcol, f32x4 acc[4][4])
{
  const int tid = threadIdx.x;
  const int l = tid & 63, w = tid >> 6;
  const int wr = (w >> 1) * 64, wc = (w & 1) * 64;
  const int srow = l >> 2;                           // row within 16-row chunk
  const int scol = ((l & 3) ^ ((l >> 3) & 3)) * 8;   // pre-swizzled global k-slot
  const int c0 = w * 2;
  const int lh = l >> 4, r15 = l & 15;

  for (int k0 = 0; k0 < D_MODEL; k0 += 32) {
#pragma unroll
    for (int i = 0; i < 2; ++i) {
      int c = c0 + i;
      gload_lds16(A + (size_t)(brow + c * 16 + srow) * D_MODEL + k0 + scol, Als + c * 512);
      gload_lds16(W + (size_t)(bcol + c * 16 + srow) * D_MODEL + k0 + scol, Bls + c * 512);
    }
    asm volatile("s_waitcnt vmcnt(0)" ::: "memory");
    __syncthreads();

    bf16x8 af[4], bfr[4];
#pragma unroll
    for (int mi = 0; mi < 4; ++mi) {
      int rr = wr + mi * 16 + r15;
      int s = lh ^ ((rr >> 1) & 3);
      af[mi] = *(const bf16x8*)(Als + rr * 32 + s * 8);
    }
#pragma unroll
    for (int ni = 0; ni < 4; ++ni) {
      int rr = wc + ni * 16 + r15;
      int s = lh ^ ((rr >> 1) & 3);
      bfr[ni] = *(const bf16x8*)(Bls + rr * 32 + s * 8);
    }
#pragma unroll
    for (int mi = 0; mi < 4; ++mi)
#pragma unroll
      for (int ni = 0; ni < 4; ++ni)
        acc[mi][ni] = __builtin_amdgcn_mfma_f32_16x16x32_bf16(af[mi], bfr[ni], acc[mi][ni], 0, 0, 0);
    __syncthreads();
  }
}

// ---------------- QKV projection: grid (32, 8, 3) ----------------
struct QKVArgs {
  const bf16_t* A;
  const bf16_t* W[3];
  const float* bias[3];
  bf16_t* out[3];
};

__global__ __launch_bounds__(256) void qkv_gemm(QKVArgs p) {
  __shared__ bf16_t Als[128 * 32], Bls[128 * 32];
  f32x4 acc[4][4];
  f32x4 zero = {0.f, 0.f, 0.f, 0.f};
#pragma unroll
  for (int i = 0; i < 4; ++i)
#pragma unroll
    for (int j = 0; j < 4; ++j) acc[i][j] = zero;

  const int z = blockIdx.z;
  const int brow = blockIdx.x * 128, bcol = blockIdx.y * 128;
  gemm_tile_128(p.A, p.W[z], Als, Bls, brow, bcol, acc);

  const int tid = threadIdx.x, l = tid & 63, w = tid >> 6;
  const int wr = (w >> 1) * 64, wc = (w & 1) * 64, lh = l >> 4, r15 = l & 15;
  const float* bias = p.bias[z];
  bf16_t* O = p.out[z];
#pragma unroll
  for (int ni = 0; ni < 4; ++ni) {
    int col = bcol + wc + ni * 16 + r15;
    float bz = bias[col];
#pragma unroll
    for (int mi = 0; mi < 4; ++mi) {
      int row0 = brow + wr + mi * 16 + lh * 4;
#pragma unroll
      for (int j = 0; j < 4; ++j)
        O[(size_t)(row0 + j) * D_MODEL + col] = (bf16_t)(acc[mi][ni][j] + bz);
    }
  }
}

// ---------------- output projection: fp32 epilogue ----------------
__global__ __launch_bounds__(256) void out_gemm(
    const bf16_t* __restrict__ A, const bf16_t* __restrict__ W,
    const float* __restrict__ bias, float* __restrict__ O)
{
  __shared__ bf16_t Als[128 * 32], Bls[128 * 32];
  f32x4 acc[4][4];
  f32x4 zero = {0.f, 0.f, 0.f, 0.f};
#pragma unroll
  for (int i = 0; i < 4; ++i)
#pragma unroll
    for (int j = 0; j < 4; ++j) acc[i][j] = zero;

  const int brow = blockIdx.x * 128, bcol = blockIdx.y * 128;
  gemm_tile_128(A, W, Als, Bls, brow, bcol, acc);

  const int tid = threadIdx.x, l = tid & 63, w = tid >> 6;
  const int wr = (w >> 1) * 64, wc = (w & 1) * 64, lh = l >> 4, r15 = l & 15;
#pragma unroll
  for (int ni = 0; ni < 4; ++ni) {
    int col = bcol + wc + ni * 16 + r15;
    float bz = bias[col];
#pragma unroll
    for (int mi = 0; mi < 4; ++mi) {
      int row0 = brow + wr + mi * 16 + lh * 4;
#pragma unroll
      for (int j = 0; j < 4; ++j)
        O[(size_t)(row0 + j) * D_MODEL + col] = acc[mi][ni][j] + bz;
    }
  }
}

// ---------------- causal flash attention ----------------
// Q,K,V,O all bf16 [B*T][1024] with head h in cols h*64..h*64+63
__global__ __launch_bounds__(256) void flash_attn(
    const bf16_t* __restrict__ Qm, const bf16_t* __restrict__ Km,
    const bf16_t* __restrict__ Vm, bf16_t* __restrict__ Om)
{
  __shared__ bf16_t Kls[64 * 64];     // [kv][d-slot swizzled]
  __shared__ bf16_t Vt[64 * 64];      // [d][kv-slot swizzled] (transposed V)
  __shared__ bf16_t Pls[4][16 * 64];  // per-wave P bounce

  const int tid = threadIdx.x, l = tid & 63, w = tid >> 6;
  const int lh = l >> 4, r15 = l & 15;
  const int qt = blockIdx.x, bh = blockIdx.y;
  const int b = bh >> 4, h = bh & 15;
  const size_t base = (size_t)b * T_SEQ * D_MODEL + h * 64;
  const int qw = qt * 64 + w * 16;   // this wave's first q row

  // Q fragments in registers: rows qw+r15, k-halves
  bf16x8 qf[2];
  {
    const bf16_t* qp = Qm + base + (size_t)(qw + r15) * D_MODEL + lh * 8;
    qf[0] = *(const bf16x8*)(qp);
    qf[1] = *(const bf16x8*)(qp + 32);
  }

  float m_r[4], l_r[4];
  f32x4 o_acc[4];
  f32x4 zero = {0.f, 0.f, 0.f, 0.f};
#pragma unroll
  for (int j = 0; j < 4; ++j) { m_r[j] = -1e30f; l_r[j] = 0.f; }
#pragma unroll
  for (int n = 0; n < 4; ++n) o_acc[n] = zero;

  bf16_t* P = &Pls[w][0];
  const int ntiles = qt + 1;
  for (int t = 0; t < ntiles; ++t) {
    const int kv0 = t * 64;
    // stage K directly to LDS, source pre-swizzled so LDS[kv][s] holds slot s^(kv&7)
#pragma unroll
    for (int i = 0; i < 2; ++i) {
      int c = w * 2 + i;
      int kvr = c * 8 + (l >> 3);
      int g8 = ((l & 7) ^ ((l >> 3) & 7)) * 8;
      gload_lds16(Km + base + (size_t)(kv0 + kvr) * D_MODEL + g8, Kls + c * 512);
    }
    // stage V transposed via registers
#pragma unroll
    for (int i = 0; i < 2; ++i) {
      int kv = (tid & 31) + i * 32;
      int g = tid >> 5;
      bf16x8 vv = *(const bf16x8*)(Vm + base + (size_t)(kv0 + kv) * D_MODEL + g * 8);
#pragma unroll
      for (int j = 0; j < 8; ++j) {
        int d = g * 8 + j;
        int ss = ((kv >> 3) ^ (d & 7) ^ ((d >> 3) & 7));
        Vt[d * 64 + ss * 8 + (kv & 7)] = vv[j];
      }
    }
    asm volatile("s_waitcnt vmcnt(0)" ::: "memory");
    __syncthreads();

    // S = Q K^T   (D[q][kv], 4 kv-frags)
    f32x4 s[4];
#pragma unroll
    for (int n = 0; n < 4; ++n) {
      int kvc = n * 16 + r15;
      f32x4 acc = zero;
#pragma unroll
      for (int kh = 0; kh < 2; ++kh) {
        int s2 = (kh * 4 + lh) ^ (kvc & 7);
        bf16x8 kf = *(const bf16x8*)(Kls + kvc * 64 + s2 * 8);
        acc = __builtin_amdgcn_mfma_f32_16x16x32_bf16(qf[kh], kf, acc, 0, 0, 0);
      }
      s[n] = acc;
    }

    // scale + causal mask + online softmax (rows = regs j, cols across 16 lanes)
    float sv[4][4];
    float pmax[4] = {-1e30f, -1e30f, -1e30f, -1e30f};
#pragma unroll
    for (int n = 0; n < 4; ++n) {
      int kvcol = kv0 + n * 16 + r15;
#pragma unroll
      for (int j = 0; j < 4; ++j) {
        float v = s[n][j] * 0.125f;
        int qrow = qw + lh * 4 + j;
        if (kvcol > qrow) v = -1e30f;
        sv[n][j] = v;
        pmax[j] = fmaxf(pmax[j], v);
      }
    }
#pragma unroll
    for (int off = 1; off < 16; off <<= 1)
#pragma unroll
      for (int j = 0; j < 4; ++j)
        pmax[j] = fmaxf(pmax[j], __shfl_xor(pmax[j], off, 64));

    float resc[4], psum[4];
#pragma unroll
    for (int j = 0; j < 4; ++j) {
      float mnew = fmaxf(m_r[j], pmax[j]);
      resc[j] = __expf(m_r[j] - mnew);
      m_r[j] = mnew;
      psum[j] = 0.f;
    }
#pragma unroll
    for (int n = 0; n < 4; ++n)
#pragma unroll
      for (int j = 0; j < 4; ++j) {
        float pv = __expf(sv[n][j] - m_r[j]);
        sv[n][j] = pv;
        psum[j] += pv;
      }
#pragma unroll
    for (int off = 1; off < 16; off <<= 1)
#pragma unroll
      for (int j = 0; j < 4; ++j)
        psum[j] += __shfl_xor(psum[j], off, 64);
#pragma unroll
    for (int j = 0; j < 4; ++j) l_r[j] = l_r[j] * resc[j] + psum[j];
#pragma unroll
    for (int n = 0; n < 4; ++n)
#pragma unroll
      for (int j = 0; j < 4; ++j)
        o_acc[n][j] *= resc[j];

    // P -> per-wave LDS (bf16, swizzled), then PV
#pragma unroll
    for (int n = 0; n < 4; ++n) {
      int kv = n * 16 + r15;
      int slot = kv >> 3;
#pragma unroll
      for (int j = 0; j < 4; ++j) {
        int q = lh * 4 + j;
        P[q * 64 + ((slot ^ (q & 7)) * 8) + (kv & 7)] = (bf16_t)sv[n][j];
      }
    }
    bf16x8 pa[2];
#pragma unroll
    for (int kh = 0; kh < 2; ++kh) {
      int ss = (kh * 4 + lh) ^ (r15 & 7);
      pa[kh] = *(const bf16x8*)(P + r15 * 64 + ss * 8);
    }
#pragma unroll
    for (int n = 0; n < 4; ++n) {
      int d = n * 16 + r15;
#pragma unroll
      for (int kh = 0; kh < 2; ++kh) {
        int ss = ((kh * 4 + lh) ^ (d & 7) ^ ((d >> 3) & 7));
        bf16x8 vf = *(const bf16x8*)(Vt + d * 64 + ss * 8);
        o_acc[n] = __builtin_amdgcn_mfma_f32_16x16x32_bf16(pa[kh], vf, o_acc[n], 0, 0, 0);
      }
    }
    __syncthreads();
  }

  // normalize + store O (bf16, [B*T][1024])
  float invl[4];
#pragma unroll
  for (int j = 0; j < 4; ++j) invl[j] = 1.f / l_r[j];
#pragma unroll
  for (int n = 0; n < 4; ++n) {
    int col = h * 64 + n * 16 + r15;
#pragma unroll
    for (int j = 0; j < 4; ++j) {
      int row = b * T_SEQ + qw + lh * 4 + j;
      Om[(size_t)row * D_MODEL + col] = (bf16_t)(o_acc[n][j] * invl[j]);
    }
  }
}

// ---------------- host launch ----------------
extern "C" void kernel_launch(void* const* d_in, const int* in_sizes, int n_in,
                              void* d_out, int out_size, void* d_ws, size_t ws_size,
                              hipStream_t stream) {
  const float* x  = (const float*)d_in[0];
  const float* wq = (const float*)d_in[1];
  const float* bq = (const float*)d_in[2];
  const float* wk = (const float*)d_in[3];
  const float* bk = (const float*)d_in[4];
  const float* wv = (const float*)d_in[5];
  const float* bv = (const float*)d_in[6];
  const float* wo = (const float*)d_in[7];
  const float* bo = (const float*)d_in[8];

  char* ws = (char*)d_ws;
  const size_t MB = 1024 * 1024;
  bf16_t* xb  = (bf16_t*)(ws);
  bf16_t* wqb = (bf16_t*)(ws + 8 * MB);
  bf16_t* wkb = (bf16_t*)(ws + 10 * MB);
  bf16_t* wvb = (bf16_t*)(ws + 12 * MB);
  bf16_t* wob = (bf16_t*)(ws + 14 * MB);
  bf16_t* qb  = (bf16_t*)(ws + 16 * MB);
  bf16_t* kb  = (bf16_t*)(ws + 24 * MB);
  bf16_t* vb  = (bf16_t*)(ws + 32 * MB);
  bf16_t* ob  = (bf16_t*)(ws + 40 * MB);

  CastArgs ca;
  ca.src[0] = x;  ca.dst[0] = xb;
  ca.src[1] = wq; ca.dst[1] = wqb;
  ca.src[2] = wk; ca.dst[2] = wkb;
  ca.src[3] = wv; ca.dst[3] = wvb;
  ca.src[4] = wo; ca.dst[4] = wob;
  cast_all<<<8192, 256, 0, stream>>>(ca);

  QKVArgs qa;
  qa.A = xb;
  qa.W[0] = wqb; qa.W[1] = wkb; qa.W[2] = wvb;
  qa.bias[0] = bq; qa.bias[1] = bk; qa.bias[2] = bv;
  qa.out[0] = qb; qa.out[1] = kb; qa.out[2] = vb;
  qkv_gemm<<<dim3(32, 8, 3), 256, 0, stream>>>(qa);

  flash_attn<<<dim3(32, 32), 256, 0, stream>>>(qb, kb, vb, ob);

  out_gemm<<<dim3(32, 8), 256, 0, stream>>>(ob, wob, bo, (float*)d_out);
}

// Round 2
// 130.303 us; speedup vs baseline: 1.6350x; 1.6350x over previous
//
#include <hip/hip_runtime.h>
#include <hip/hip_bf16.h>

typedef __bf16 bf16_t;
typedef __bf16 bf16x8 __attribute__((ext_vector_type(8)));
typedef __bf16 bf16x4 __attribute__((ext_vector_type(4)));
typedef float f32x4 __attribute__((ext_vector_type(4)));
typedef unsigned int u32;

#define D_MODEL 1024
#define T_SEQ   2048
#define N_HEADS 16

#define WAITVM(N) asm volatile("s_waitcnt vmcnt(" #N ")" ::: "memory")

__device__ __forceinline__ void gload_lds16(const void* g, void* l) {
  __builtin_amdgcn_global_load_lds((const __attribute__((address_space(1))) u32*)g,
                                   (__attribute__((address_space(3))) u32*)l, 16, 0, 0);
}

// ---------------- fused fp32->bf16 cast (x + 4 weights) ----------------
struct CastArgs { const float* src[5]; bf16_t* dst[5]; };

__global__ __launch_bounds__(256) void cast_all(CastArgs p) {
  unsigned i = (blockIdx.x * 256u + threadIdx.x) * 4u;
  int seg; unsigned off;
  if (i < 4194304u) { seg = 0; off = i; }
  else { unsigned r = i - 4194304u; seg = 1 + (int)(r >> 20); off = r & 1048575u; }
  const float4 v = *(const float4*)(p.src[seg] + off);
  bf16x4 o = { (bf16_t)v.x, (bf16_t)v.y, (bf16_t)v.z, (bf16_t)v.w };
  *(bf16x4*)(p.dst[seg] + off) = o;
}

// ---------------- 128x128 bf16 GEMM tile, C = A @ W^T ----------------
__device__ __forceinline__ void gemm_tile_128(
    const bf16_t* __restrict__ A, const bf16_t* __restrict__ W,
    bf16_t* Als, bf16_t* Bls, int brow, int bcol, f32x4 acc[4][4])
{
  const int tid = threadIdx.x;
  const int l = tid & 63, w = tid >> 6;
  const int wr = (w >> 1) * 64, wc = (w & 1) * 64;
  const int srow = l >> 2;
  const int scol = ((l & 3) ^ ((l >> 3) & 3)) * 8;
  const int c0 = w * 2;
  const int lh = l >> 4, r15 = l & 15;

  for (int k0 = 0; k0 < D_MODEL; k0 += 32) {
#pragma unroll
    for (int i = 0; i < 2; ++i) {
      int c = c0 + i;
      gload_lds16(A + (size_t)(brow + c * 16 + srow) * D_MODEL + k0 + scol, Als + c * 512);
      gload_lds16(W + (size_t)(bcol + c * 16 + srow) * D_MODEL + k0 + scol, Bls + c * 512);
    }
    asm volatile("s_waitcnt vmcnt(0)" ::: "memory");
    __syncthreads();

    bf16x8 af[4], bfr[4];
#pragma unroll
    for (int mi = 0; mi < 4; ++mi) {
      int rr = wr + mi * 16 + r15;
      int s = lh ^ ((rr >> 1) & 3);
      af[mi] = *(const bf16x8*)(Als + rr * 32 + s * 8);
    }
#pragma unroll
    for (int ni = 0; ni < 4; ++ni) {
      int rr = wc + ni * 16 + r15;
      int s = lh ^ ((rr >> 1) & 3);
      bfr[ni] = *(const bf16x8*)(Bls + rr * 32 + s * 8);
    }
#pragma unroll
    for (int mi = 0; mi < 4; ++mi)
#pragma unroll
      for (int ni = 0; ni < 4; ++ni)
        acc[mi][ni] = __builtin_amdgcn_mfma_f32_16x16x32_bf16(af[mi], bfr[ni], acc[mi][ni], 0, 0, 0);
    __syncthreads();
  }
}

// ---------------- QKV projection: grid (32, 8, 3) ----------------
// z==2 (V) writes TRANSPOSED: vt[b][dcol][t]  (dcol = 0..1023, t = 0..2047)
struct QKVArgs {
  const bf16_t* A;
  const bf16_t* W[3];
  const float* bias[3];
  bf16_t* out[3];   // out[2] = V^T base
};

__global__ __launch_bounds__(256) void qkv_gemm(QKVArgs p) {
  __shared__ bf16_t Als[128 * 32], Bls[128 * 32];
  f32x4 acc[4][4];
  f32x4 zero = {0.f, 0.f, 0.f, 0.f};
#pragma unroll
  for (int i = 0; i < 4; ++i)
#pragma unroll
    for (int j = 0; j < 4; ++j) acc[i][j] = zero;

  const int z = blockIdx.z;
  const int brow = blockIdx.x * 128, bcol = blockIdx.y * 128;
  gemm_tile_128(p.A, p.W[z], Als, Bls, brow, bcol, acc);

  const int tid = threadIdx.x, l = tid & 63, w = tid >> 6;
  const int wr = (w >> 1) * 64, wc = (w & 1) * 64, lh = l >> 4, r15 = l & 15;
  const float* bias = p.bias[z];
  bf16_t* O = p.out[z];

  if (z == 2) {
    // transposed store: V^T[b][col][t], 4 consecutive t per lane -> bf16x4
#pragma unroll
    for (int ni = 0; ni < 4; ++ni) {
      int col = bcol + wc + ni * 16 + r15;
      float bz = bias[col];
#pragma unroll
      for (int mi = 0; mi < 4; ++mi) {
        int row0 = brow + wr + mi * 16 + lh * 4;
        int bb = row0 >> 11, t0 = row0 & 2047;
        bf16x4 pk;
#pragma unroll
        for (int j = 0; j < 4; ++j) pk[j] = (bf16_t)(acc[mi][ni][j] + bz);
        *(bf16x4*)(O + (size_t)bb * (D_MODEL * T_SEQ) + (size_t)col * T_SEQ + t0) = pk;
      }
    }
  } else {
#pragma unroll
    for (int ni = 0; ni < 4; ++ni) {
      int col = bcol + wc + ni * 16 + r15;
      float bz = bias[col];
#pragma unroll
      for (int mi = 0; mi < 4; ++mi) {
        int row0 = brow + wr + mi * 16 + lh * 4;
#pragma unroll
        for (int j = 0; j < 4; ++j)
          O[(size_t)(row0 + j) * D_MODEL + col] = (bf16_t)(acc[mi][ni][j] + bz);
      }
    }
  }
}

// ---------------- output projection: fp32 epilogue ----------------
__global__ __launch_bounds__(256) void out_gemm(
    const bf16_t* __restrict__ A, const bf16_t* __restrict__ W,
    const float* __restrict__ bias, float* __restrict__ O)
{
  __shared__ bf16_t Als[128 * 32], Bls[128 * 32];
  f32x4 acc[4][4];
  f32x4 zero = {0.f, 0.f, 0.f, 0.f};
#pragma unroll
  for (int i = 0; i < 4; ++i)
#pragma unroll
    for (int j = 0; j < 4; ++j) acc[i][j] = zero;

  const int brow = blockIdx.x * 128, bcol = blockIdx.y * 128;
  gemm_tile_128(A, W, Als, Bls, brow, bcol, acc);

  const int tid = threadIdx.x, l = tid & 63, w = tid >> 6;
  const int wr = (w >> 1) * 64, wc = (w & 1) * 64, lh = l >> 4, r15 = l & 15;
#pragma unroll
  for (int ni = 0; ni < 4; ++ni) {
    int col = bcol + wc + ni * 16 + r15;
    float bz = bias[col];
#pragma unroll
    for (int mi = 0; mi < 4; ++mi) {
      int row0 = brow + wr + mi * 16 + lh * 4;
#pragma unroll
      for (int j = 0; j < 4; ++j)
        O[(size_t)(row0 + j) * D_MODEL + col] = acc[mi][ni][j] + bz;
    }
  }
}

// ---------------- causal flash attention ----------------
// Q,K row-major [B*T][1024]; Vt transposed [B][1024][2048]; O bf16 [B*T][1024]
// 4 waves x 32 q-rows = 128 q/block; KV tile = 64; dbuf K/V staging; m=0 softmax.
__device__ __forceinline__ void stage_kv(const bf16_t* Kg, const bf16_t* Vg,
                                         bf16_t* Kd, bf16_t* Vd, int kv0, int w, int l) {
#pragma unroll
  for (int i = 0; i < 2; ++i) {
    int c = w * 2 + i;
    int rr = c * 8 + (l >> 3);
    int gcol = ((l & 7) ^ ((l >> 3) & 7)) * 8;
    gload_lds16(Kg + (size_t)(kv0 + rr) * D_MODEL + gcol, Kd + c * 512);
    gload_lds16(Vg + (size_t)rr * T_SEQ + kv0 + gcol, Vd + c * 512);
  }
}

__global__ __launch_bounds__(256) void flash_attn(
    const bf16_t* __restrict__ Qm, const bf16_t* __restrict__ Km,
    const bf16_t* __restrict__ Vtg, bf16_t* __restrict__ Om)
{
  __shared__ bf16_t Kls[2][64 * 64];
  __shared__ bf16_t Vls[2][64 * 64];
  __shared__ bf16_t Pls[4][32 * 64];

  const int tid = threadIdx.x, l = tid & 63, w = tid >> 6;
  const int lh = l >> 4, r15 = l & 15;

  // XCD-clustered decode: xcd = bh%8; within XCD, big qt first (LPT greedy)
  const int lid = blockIdx.x;
  const int xcd = lid & 7, rem = lid >> 3;
  const int qt = 15 - (rem & 15);
  const int bh = xcd + 8 * (rem >> 4);
  const int b = bh >> 4, h = bh & 15;
  const size_t baseQ = (size_t)b * T_SEQ * D_MODEL + h * 64;
  const size_t baseVt = (size_t)b * (D_MODEL * T_SEQ) + (size_t)(h * 64) * T_SEQ;
  const int qw = qt * 128 + w * 32;

  // Q fragments qf[mi][kh]: rows qw+mi*16+r15, k = kh*32+lh*8
  bf16x8 qf[2][2];
#pragma unroll
  for (int mi = 0; mi < 2; ++mi) {
    const bf16_t* qp = Qm + baseQ + (size_t)(qw + mi * 16 + r15) * D_MODEL + lh * 8;
    qf[mi][0] = *(const bf16x8*)(qp);
    qf[mi][1] = *(const bf16x8*)(qp + 32);
  }

  float l_r[2][4];
  f32x4 o_acc[2][4];
  const f32x4 zero = {0.f, 0.f, 0.f, 0.f};
#pragma unroll
  for (int mi = 0; mi < 2; ++mi) {
#pragma unroll
    for (int j = 0; j < 4; ++j) l_r[mi][j] = 0.f;
#pragma unroll
    for (int n = 0; n < 4; ++n) o_acc[mi][n] = zero;
  }

  bf16_t* P = &Pls[w][0];
  const bf16_t* Kg = Km + baseQ;
  const bf16_t* Vg = Vtg + baseVt;
  const int ntiles = qt * 2 + 2;

  stage_kv(Kg, Vg, Kls[0], Vls[0], 0, w, l);

  for (int t = 0; t < ntiles; ++t) {
    const int buf = t & 1;
    if (t + 1 < ntiles) {
      stage_kv(Kg, Vg, Kls[buf ^ 1], Vls[buf ^ 1], (t + 1) * 64, w, l);
      WAITVM(4);
    } else {
      WAITVM(0);
    }
    __builtin_amdgcn_s_barrier();

    const int kv0 = t * 64;
    if (kv0 <= qw + 31) {
      const bf16_t* Kb = Kls[buf];
      const bf16_t* Vb = Vls[buf];

      // ---- S = Q K^T ----
      f32x4 sf[2][4];
#pragma unroll
      for (int n = 0; n < 4; ++n) {
        const int kvc = n * 16 + r15;
        const int sw = kvc & 7;
        bf16x8 kf0 = *(const bf16x8*)(Kb + kvc * 64 + ((lh ^ sw) * 8));
        bf16x8 kf1 = *(const bf16x8*)(Kb + kvc * 64 + (((4 + lh) ^ sw) * 8));
#pragma unroll
        for (int mi = 0; mi < 2; ++mi) {
          f32x4 a = zero;
          a = __builtin_amdgcn_mfma_f32_16x16x32_bf16(qf[mi][0], kf0, a, 0, 0, 0);
          a = __builtin_amdgcn_mfma_f32_16x16x32_bf16(qf[mi][1], kf1, a, 0, 0, 0);
          sf[mi][n] = a;
        }
      }

      // ---- p = exp(s/8) (m=0), mask, accumulate l, pack P to LDS ----
#pragma unroll
      for (int mi = 0; mi < 2; ++mi)
#pragma unroll
        for (int n = 0; n < 4; ++n) {
          const int kvcol = kv0 + n * 16 + r15;
          const int slot = (n * 16 + r15) >> 3;
#pragma unroll
          for (int j = 0; j < 4; ++j) {
            const int qrow = qw + mi * 16 + lh * 4 + j;
            float p = __expf(sf[mi][n][j] * 0.125f);
            if (kvcol > qrow) p = 0.f;
            l_r[mi][j] += p;
            const int q7 = (lh * 4 + j) & 7;
            P[(mi * 16 + lh * 4 + j) * 64 + ((slot ^ q7) * 8) + (r15 & 7)] = (bf16_t)p;
          }
        }

      // ---- O += P V ----
      bf16x8 pa[2][2];
#pragma unroll
      for (int mi = 0; mi < 2; ++mi) {
        const int rp = mi * 16 + r15;
        const int sw = r15 & 7;
        pa[mi][0] = *(const bf16x8*)(P + rp * 64 + ((lh ^ sw) * 8));
        pa[mi][1] = *(const bf16x8*)(P + rp * 64 + (((4 + lh) ^ sw) * 8));
      }
#pragma unroll
      for (int n = 0; n < 4; ++n) {
        const int d = n * 16 + r15;
        const int sw = d & 7;
        bf16x8 vf0 = *(const bf16x8*)(Vb + d * 64 + ((lh ^ sw) * 8));
        bf16x8 vf1 = *(const bf16x8*)(Vb + d * 64 + (((4 + lh) ^ sw) * 8));
#pragma unroll
        for (int mi = 0; mi < 2; ++mi) {
          o_acc[mi][n] = __builtin_amdgcn_mfma_f32_16x16x32_bf16(pa[mi][0], vf0, o_acc[mi][n], 0, 0, 0);
          o_acc[mi][n] = __builtin_amdgcn_mfma_f32_16x16x32_bf16(pa[mi][1], vf1, o_acc[mi][n], 0, 0, 0);
        }
      }
    }
    __builtin_amdgcn_s_barrier();
  }

  // final l reduction over the 16-lane (r15) axis, once
#pragma unroll
  for (int off = 1; off < 16; off <<= 1)
#pragma unroll
    for (int mi = 0; mi < 2; ++mi)
#pragma unroll
      for (int j = 0; j < 4; ++j)
        l_r[mi][j] += __shfl_xor(l_r[mi][j], off, 64);

  float invl[2][4];
#pragma unroll
  for (int mi = 0; mi < 2; ++mi)
#pragma unroll
    for (int j = 0; j < 4; ++j) invl[mi][j] = 1.f / l_r[mi][j];

#pragma unroll
  for (int mi = 0; mi < 2; ++mi)
#pragma unroll
    for (int n = 0; n < 4; ++n) {
      int col = h * 64 + n * 16 + r15;
#pragma unroll
      for (int j = 0; j < 4; ++j) {
        int row = b * T_SEQ + qw + mi * 16 + lh * 4 + j;
        Om[(size_t)row * D_MODEL + col] = (bf16_t)(o_acc[mi][n][j] * invl[mi][j]);
      }
    }
}

// ---------------- host launch ----------------
extern "C" void kernel_launch(void* const* d_in, const int* in_sizes, int n_in,
                              void* d_out, int out_size, void* d_ws, size_t ws_size,
                              hipStream_t stream) {
  const float* x  = (const float*)d_in[0];
  const float* wq = (const float*)d_in[1];
  const float* bq = (const float*)d_in[2];
  const float* wk = (const float*)d_in[3];
  const float* bk = (const float*)d_in[4];
  const float* wv = (const float*)d_in[5];
  const float* bv = (const float*)d_in[6];
  const float* wo = (const float*)d_in[7];
  const float* bo = (const float*)d_in[8];

  char* ws = (char*)d_ws;
  const size_t MB = 1024 * 1024;
  bf16_t* xb  = (bf16_t*)(ws);
  bf16_t* wqb = (bf16_t*)(ws + 8 * MB);
  bf16_t* wkb = (bf16_t*)(ws + 10 * MB);
  bf16_t* wvb = (bf16_t*)(ws + 12 * MB);
  bf16_t* wob = (bf16_t*)(ws + 14 * MB);
  bf16_t* qb  = (bf16_t*)(ws + 16 * MB);
  bf16_t* kb  = (bf16_t*)(ws + 24 * MB);
  bf16_t* vtb = (bf16_t*)(ws + 32 * MB);  // V^T [B][1024][2048]
  bf16_t* ob  = (bf16_t*)(ws + 40 * MB);

  CastArgs ca;
  ca.src[0] = x;  ca.dst[0] = xb;
  ca.src[1] = wq; ca.dst[1] = wqb;
  ca.src[2] = wk; ca.dst[2] = wkb;
  ca.src[3] = wv; ca.dst[3] = wvb;
  ca.src[4] = wo; ca.dst[4] = wob;
  cast_all<<<8192, 256, 0, stream>>>(ca);

  QKVArgs qa;
  qa.A = xb;
  qa.W[0] = wqb; qa.W[1] = wkb; qa.W[2] = wvb;
  qa.bias[0] = bq; qa.bias[1] = bk; qa.bias[2] = bv;
  qa.out[0] = qb; qa.out[1] = kb; qa.out[2] = vtb;
  qkv_gemm<<<dim3(32, 8, 3), 256, 0, stream>>>(qa);

  flash_attn<<<512, 256, 0, stream>>>(qb, kb, vtb, ob);

  out_gemm<<<dim3(32, 8), 256, 0, stream>>>(ob, wob, bo, (float*)d_out);
}

// Round 3
// 116.265 us; speedup vs baseline: 1.8324x; 1.1207x over previous
//
#include <hip/hip_runtime.h>
#include <hip/hip_bf16.h>

typedef __bf16 bf16_t;
typedef __bf16 bf16x8 __attribute__((ext_vector_type(8)));
typedef __bf16 bf16x4 __attribute__((ext_vector_type(4)));
typedef float f32x4 __attribute__((ext_vector_type(4)));
typedef unsigned int u32;

#define D_MODEL 1024
#define T_SEQ   2048
#define N_HEADS 16

#define WAITVM(N) asm volatile("s_waitcnt vmcnt(" #N ")" ::: "memory")

__device__ __forceinline__ void gload_lds16(const void* g, void* l) {
  __builtin_amdgcn_global_load_lds((const __attribute__((address_space(1))) u32*)g,
                                   (__attribute__((address_space(3))) u32*)l, 16, 0, 0);
}

// ---------------- fused fp32->bf16 cast (x + 4 weights) ----------------
struct CastArgs { const float* src[5]; bf16_t* dst[5]; };

__global__ __launch_bounds__(256) void cast_all(CastArgs p) {
  unsigned i = (blockIdx.x * 256u + threadIdx.x) * 4u;
  int seg; unsigned off;
  if (i < 4194304u) { seg = 0; off = i; }
  else { unsigned r = i - 4194304u; seg = 1 + (int)(r >> 20); off = r & 1048575u; }
  const float4 v = *(const float4*)(p.src[seg] + off);
  bf16x4 o = { (bf16_t)v.x, (bf16_t)v.y, (bf16_t)v.z, (bf16_t)v.w };
  *(bf16x4*)(p.dst[seg] + off) = o;
}

// ---------------- 128x128 bf16 GEMM tile, C = A @ W^T ----------------
__device__ __forceinline__ void gemm_tile_128(
    const bf16_t* __restrict__ A, const bf16_t* __restrict__ W,
    bf16_t* Als, bf16_t* Bls, int brow, int bcol, f32x4 acc[4][4])
{
  const int tid = threadIdx.x;
  const int l = tid & 63, w = tid >> 6;
  const int wr = (w >> 1) * 64, wc = (w & 1) * 64;
  const int srow = l >> 2;
  const int scol = ((l & 3) ^ ((l >> 3) & 3)) * 8;
  const int c0 = w * 2;
  const int lh = l >> 4, r15 = l & 15;

  for (int k0 = 0; k0 < D_MODEL; k0 += 32) {
#pragma unroll
    for (int i = 0; i < 2; ++i) {
      int c = c0 + i;
      gload_lds16(A + (size_t)(brow + c * 16 + srow) * D_MODEL + k0 + scol, Als + c * 512);
      gload_lds16(W + (size_t)(bcol + c * 16 + srow) * D_MODEL + k0 + scol, Bls + c * 512);
    }
    asm volatile("s_waitcnt vmcnt(0)" ::: "memory");
    __syncthreads();

    bf16x8 af[4], bfr[4];
#pragma unroll
    for (int mi = 0; mi < 4; ++mi) {
      int rr = wr + mi * 16 + r15;
      int s = lh ^ ((rr >> 1) & 3);
      af[mi] = *(const bf16x8*)(Als + rr * 32 + s * 8);
    }
#pragma unroll
    for (int ni = 0; ni < 4; ++ni) {
      int rr = wc + ni * 16 + r15;
      int s = lh ^ ((rr >> 1) & 3);
      bfr[ni] = *(const bf16x8*)(Bls + rr * 32 + s * 8);
    }
#pragma unroll
    for (int mi = 0; mi < 4; ++mi)
#pragma unroll
      for (int ni = 0; ni < 4; ++ni)
        acc[mi][ni] = __builtin_amdgcn_mfma_f32_16x16x32_bf16(af[mi], bfr[ni], acc[mi][ni], 0, 0, 0);
    __syncthreads();
  }
}

// ---------------- QKV projection: grid (32, 8, 3) ----------------
// z==2 (V) writes TRANSPOSED: vt[b][dcol][t]
struct QKVArgs {
  const bf16_t* A;
  const bf16_t* W[3];
  const float* bias[3];
  bf16_t* out[3];   // out[2] = V^T base
};

__global__ __launch_bounds__(256) void qkv_gemm(QKVArgs p) {
  __shared__ bf16_t Als[128 * 32], Bls[128 * 32];
  f32x4 acc[4][4];
  f32x4 zero = {0.f, 0.f, 0.f, 0.f};
#pragma unroll
  for (int i = 0; i < 4; ++i)
#pragma unroll
    for (int j = 0; j < 4; ++j) acc[i][j] = zero;

  const int z = blockIdx.z;
  const int brow = blockIdx.x * 128, bcol = blockIdx.y * 128;
  gemm_tile_128(p.A, p.W[z], Als, Bls, brow, bcol, acc);

  const int tid = threadIdx.x, l = tid & 63, w = tid >> 6;
  const int wr = (w >> 1) * 64, wc = (w & 1) * 64, lh = l >> 4, r15 = l & 15;
  const float* bias = p.bias[z];
  bf16_t* O = p.out[z];

  if (z == 2) {
#pragma unroll
    for (int ni = 0; ni < 4; ++ni) {
      int col = bcol + wc + ni * 16 + r15;
      float bz = bias[col];
#pragma unroll
      for (int mi = 0; mi < 4; ++mi) {
        int row0 = brow + wr + mi * 16 + lh * 4;
        int bb = row0 >> 11, t0 = row0 & 2047;
        bf16x4 pk;
#pragma unroll
        for (int j = 0; j < 4; ++j) pk[j] = (bf16_t)(acc[mi][ni][j] + bz);
        *(bf16x4*)(O + (size_t)bb * (D_MODEL * T_SEQ) + (size_t)col * T_SEQ + t0) = pk;
      }
    }
  } else {
#pragma unroll
    for (int ni = 0; ni < 4; ++ni) {
      int col = bcol + wc + ni * 16 + r15;
      float bz = bias[col];
#pragma unroll
      for (int mi = 0; mi < 4; ++mi) {
        int row0 = brow + wr + mi * 16 + lh * 4;
#pragma unroll
        for (int j = 0; j < 4; ++j)
          O[(size_t)(row0 + j) * D_MODEL + col] = (bf16_t)(acc[mi][ni][j] + bz);
      }
    }
  }
}

// ---------------- output projection: fp32 epilogue ----------------
__global__ __launch_bounds__(256) void out_gemm(
    const bf16_t* __restrict__ A, const bf16_t* __restrict__ W,
    const float* __restrict__ bias, float* __restrict__ O)
{
  __shared__ bf16_t Als[128 * 32], Bls[128 * 32];
  f32x4 acc[4][4];
  f32x4 zero = {0.f, 0.f, 0.f, 0.f};
#pragma unroll
  for (int i = 0; i < 4; ++i)
#pragma unroll
    for (int j = 0; j < 4; ++j) acc[i][j] = zero;

  const int brow = blockIdx.x * 128, bcol = blockIdx.y * 128;
  gemm_tile_128(A, W, Als, Bls, brow, bcol, acc);

  const int tid = threadIdx.x, l = tid & 63, w = tid >> 6;
  const int wr = (w >> 1) * 64, wc = (w & 1) * 64, lh = l >> 4, r15 = l & 15;
#pragma unroll
  for (int ni = 0; ni < 4; ++ni) {
    int col = bcol + wc + ni * 16 + r15;
    float bz = bias[col];
#pragma unroll
    for (int mi = 0; mi < 4; ++mi) {
      int row0 = brow + wr + mi * 16 + lh * 4;
#pragma unroll
      for (int j = 0; j < 4; ++j)
        O[(size_t)(row0 + j) * D_MODEL + col] = acc[mi][ni][j] + bz;
    }
  }
}

// ---------------- causal flash attention ----------------
// Q,K row-major [B*T][1024]; Vt transposed [B][1024][2048]; O bf16 [B*T][1024]
__device__ __forceinline__ void stage_kv(const bf16_t* Kg, const bf16_t* Vg,
                                         bf16_t* Kd, bf16_t* Vd, int kv0, int w, int l) {
#pragma unroll
  for (int i = 0; i < 2; ++i) {
    int c = w * 2 + i;
    int rr = c * 8 + (l >> 3);
    int gcol = ((l & 7) ^ ((l >> 3) & 7)) * 8;
    gload_lds16(Kg + (size_t)(kv0 + rr) * D_MODEL + gcol, Kd + c * 512);
    gload_lds16(Vg + (size_t)rr * T_SEQ + kv0 + gcol, Vd + c * 512);
  }
}

__global__ __launch_bounds__(256) void flash_attn(
    const bf16_t* __restrict__ Qm, const bf16_t* __restrict__ Km,
    const bf16_t* __restrict__ Vtg, bf16_t* __restrict__ Om)
{
  __shared__ bf16_t Kls[2][64 * 64];
  __shared__ bf16_t Vls[2][64 * 64];
  __shared__ bf16_t Pls[4][32 * 64];

  const int tid = threadIdx.x, l = tid & 63, w = tid >> 6;
  const int lh = l >> 4, r15 = l & 15;

  // Balanced decode: blocks lid and lid+256 land on the same CU under
  // round-robin dispatch -> give them complementary qt (a, 15-a).
  // Big half (rnd=0 -> qt=15-q3 in 8..15) dispatches first.
  const int lid = blockIdx.x;
  const int xcd = lid & 7;
  const int h2  = (lid >> 3) & 3;
  const int q3  = (lid >> 5) & 7;
  const int rnd = lid >> 8;
  const int qt  = rnd ? q3 : 15 - q3;
  const int bh  = xcd + 8 * h2;
  const int b = bh >> 4, h = bh & 15;
  const size_t baseQ = (size_t)b * T_SEQ * D_MODEL + h * 64;
  const size_t baseVt = (size_t)b * (D_MODEL * T_SEQ) + (size_t)(h * 64) * T_SEQ;
  const int qw = qt * 128 + w * 32;

  // Q fragments qf[mi][kh]: rows qw+mi*16+r15, k = kh*32+lh*8
  bf16x8 qf[2][2];
#pragma unroll
  for (int mi = 0; mi < 2; ++mi) {
    const bf16_t* qp = Qm + baseQ + (size_t)(qw + mi * 16 + r15) * D_MODEL + lh * 8;
    qf[mi][0] = *(const bf16x8*)(qp);
    qf[mi][1] = *(const bf16x8*)(qp + 32);
  }

  float l_r[2][4];
  f32x4 o_acc[2][4];
  const f32x4 zero = {0.f, 0.f, 0.f, 0.f};
#pragma unroll
  for (int mi = 0; mi < 2; ++mi) {
#pragma unroll
    for (int j = 0; j < 4; ++j) l_r[mi][j] = 0.f;
#pragma unroll
    for (int n = 0; n < 4; ++n) o_acc[mi][n] = zero;
  }

  bf16_t* P = &Pls[w][0];
  const bf16_t* Kg = Km + baseQ;
  const bf16_t* Vg = Vtg + baseVt;
  const int ntiles = qt * 2 + 2;

  stage_kv(Kg, Vg, Kls[0], Vls[0], 0, w, l);

  for (int t = 0; t < ntiles; ++t) {
    const int buf = t & 1;
    if (t + 1 < ntiles) {
      stage_kv(Kg, Vg, Kls[buf ^ 1], Vls[buf ^ 1], (t + 1) * 64, w, l);
      WAITVM(4);
    } else {
      WAITVM(0);
    }
    __builtin_amdgcn_s_barrier();

    const int kv0 = t * 64;
    if (kv0 <= qw + 31) {
      const bf16_t* Kb = Kls[buf];
      const bf16_t* Vb = Vls[buf];

      // ---- S = Q K^T ----
      f32x4 sf[2][4];
      __builtin_amdgcn_s_setprio(1);
#pragma unroll
      for (int n = 0; n < 4; ++n) {
        const int kvc = n * 16 + r15;
        const int sw = kvc & 7;
        bf16x8 kf0 = *(const bf16x8*)(Kb + kvc * 64 + ((lh ^ sw) * 8));
        bf16x8 kf1 = *(const bf16x8*)(Kb + kvc * 64 + (((4 + lh) ^ sw) * 8));
#pragma unroll
        for (int mi = 0; mi < 2; ++mi) {
          f32x4 a = zero;
          a = __builtin_amdgcn_mfma_f32_16x16x32_bf16(qf[mi][0], kf0, a, 0, 0, 0);
          a = __builtin_amdgcn_mfma_f32_16x16x32_bf16(qf[mi][1], kf1, a, 0, 0, 0);
          sf[mi][n] = a;
        }
      }
      __builtin_amdgcn_s_setprio(0);

      // ---- p = exp(s/8) (m=0), mask only on diagonal tiles ----
      if (kv0 + 63 > qw) {
#pragma unroll
        for (int mi = 0; mi < 2; ++mi)
#pragma unroll
          for (int n = 0; n < 4; ++n) {
            const int kvcol = kv0 + n * 16 + r15;
            const int slot = (n * 16 + r15) >> 3;
#pragma unroll
            for (int j = 0; j < 4; ++j) {
              const int qrow = qw + mi * 16 + lh * 4 + j;
              float p = __expf(sf[mi][n][j] * 0.125f);
              if (kvcol > qrow) p = 0.f;
              l_r[mi][j] += p;
              const int q7 = (lh * 4 + j) & 7;
              P[(mi * 16 + lh * 4 + j) * 64 + ((slot ^ q7) * 8) + (r15 & 7)] = (bf16_t)p;
            }
          }
      } else {
#pragma unroll
        for (int mi = 0; mi < 2; ++mi)
#pragma unroll
          for (int n = 0; n < 4; ++n) {
            const int slot = (n * 16 + r15) >> 3;
#pragma unroll
            for (int j = 0; j < 4; ++j) {
              float p = __expf(sf[mi][n][j] * 0.125f);
              l_r[mi][j] += p;
              const int q7 = (lh * 4 + j) & 7;
              P[(mi * 16 + lh * 4 + j) * 64 + ((slot ^ q7) * 8) + (r15 & 7)] = (bf16_t)p;
            }
          }
      }

      // ---- O += P V ----
      bf16x8 pa[2][2];
#pragma unroll
      for (int mi = 0; mi < 2; ++mi) {
        const int rp = mi * 16 + r15;
        const int sw = r15 & 7;
        pa[mi][0] = *(const bf16x8*)(P + rp * 64 + ((lh ^ sw) * 8));
        pa[mi][1] = *(const bf16x8*)(P + rp * 64 + (((4 + lh) ^ sw) * 8));
      }
      __builtin_amdgcn_s_setprio(1);
#pragma unroll
      for (int n = 0; n < 4; ++n) {
        const int d = n * 16 + r15;
        const int sw = d & 7;
        bf16x8 vf0 = *(const bf16x8*)(Vb + d * 64 + ((lh ^ sw) * 8));
        bf16x8 vf1 = *(const bf16x8*)(Vb + d * 64 + (((4 + lh) ^ sw) * 8));
#pragma unroll
        for (int mi = 0; mi < 2; ++mi) {
          o_acc[mi][n] = __builtin_amdgcn_mfma_f32_16x16x32_bf16(pa[mi][0], vf0, o_acc[mi][n], 0, 0, 0);
          o_acc[mi][n] = __builtin_amdgcn_mfma_f32_16x16x32_bf16(pa[mi][1], vf1, o_acc[mi][n], 0, 0, 0);
        }
      }
      __builtin_amdgcn_s_setprio(0);
    }
    __builtin_amdgcn_s_barrier();
  }

  // final l reduction over the 16-lane (r15) axis, once
#pragma unroll
  for (int off = 1; off < 16; off <<= 1)
#pragma unroll
    for (int mi = 0; mi < 2; ++mi)
#pragma unroll
      for (int j = 0; j < 4; ++j)
        l_r[mi][j] += __shfl_xor(l_r[mi][j], off, 64);

  float invl[2][4];
#pragma unroll
  for (int mi = 0; mi < 2; ++mi)
#pragma unroll
    for (int j = 0; j < 4; ++j) invl[mi][j] = 1.f / l_r[mi][j];

#pragma unroll
  for (int mi = 0; mi < 2; ++mi)
#pragma unroll
    for (int n = 0; n < 4; ++n) {
      int col = h * 64 + n * 16 + r15;
#pragma unroll
      for (int j = 0; j < 4; ++j) {
        int row = b * T_SEQ + qw + mi * 16 + lh * 4 + j;
        Om[(size_t)row * D_MODEL + col] = (bf16_t)(o_acc[mi][n][j] * invl[mi][j]);
      }
    }
}

// ---------------- host launch ----------------
extern "C" void kernel_launch(void* const* d_in, const int* in_sizes, int n_in,
                              void* d_out, int out_size, void* d_ws, size_t ws_size,
                              hipStream_t stream) {
  const float* x  = (const float*)d_in[0];
  const float* wq = (const float*)d_in[1];
  const float* bq = (const float*)d_in[2];
  const float* wk = (const float*)d_in[3];
  const float* bk = (const float*)d_in[4];
  const float* wv = (const float*)d_in[5];
  const float* bv = (const float*)d_in[6];
  const float* wo = (const float*)d_in[7];
  const float* bo = (const float*)d_in[8];

  char* ws = (char*)d_ws;
  const size_t MB = 1024 * 1024;
  bf16_t* xb  = (bf16_t*)(ws);
  bf16_t* wqb = (bf16_t*)(ws + 8 * MB);
  bf16_t* wkb = (bf16_t*)(ws + 10 * MB);
  bf16_t* wvb = (bf16_t*)(ws + 12 * MB);
  bf16_t* wob = (bf16_t*)(ws + 14 * MB);
  bf16_t* qb  = (bf16_t*)(ws + 16 * MB);
  bf16_t* kb  = (bf16_t*)(ws + 24 * MB);
  bf16_t* vtb = (bf16_t*)(ws + 32 * MB);  // V^T [B][1024][2048]
  bf16_t* ob  = (bf16_t*)(ws + 40 * MB);

  CastArgs ca;
  ca.src[0] = x;  ca.dst[0] = xb;
  ca.src[1] = wq; ca.dst[1] = wqb;
  ca.src[2] = wk; ca.dst[2] = wkb;
  ca.src[3] = wv; ca.dst[3] = wvb;
  ca.src[4] = wo; ca.dst[4] = wob;
  cast_all<<<8192, 256, 0, stream>>>(ca);

  QKVArgs qa;
  qa.A = xb;
  qa.W[0] = wqb; qa.W[1] = wkb; qa.W[2] = wvb;
  qa.bias[0] = bq; qa.bias[1] = bk; qa.bias[2] = bv;
  qa.out[0] = qb; qa.out[1] = kb; qa.out[2] = vtb;
  qkv_gemm<<<dim3(32, 8, 3), 256, 0, stream>>>(qa);

  flash_attn<<<512, 256, 0, stream>>>(qb, kb, vtb, ob);

  out_gemm<<<dim3(32, 8), 256, 0, stream>>>(ob, wob, bo, (float*)d_out);
}

// Round 4
// 114.799 us; speedup vs baseline: 1.8558x; 1.0128x over previous
//
#include <hip/hip_runtime.h>
#include <hip/hip_bf16.h>

typedef __bf16 bf16_t;
typedef __bf16 bf16x8 __attribute__((ext_vector_type(8)));
typedef __bf16 bf16x4 __attribute__((ext_vector_type(4)));
typedef float f32x4 __attribute__((ext_vector_type(4)));
typedef unsigned int u32;

#define D_MODEL 1024
#define T_SEQ   2048
#define N_HEADS 16

#define WAITVM(N) asm volatile("s_waitcnt vmcnt(" #N ")" ::: "memory")

__device__ __forceinline__ void gload_lds16(const void* g, void* l) {
  __builtin_amdgcn_global_load_lds((const __attribute__((address_space(1))) u32*)g,
                                   (__attribute__((address_space(3))) u32*)l, 16, 0, 0);
}

// ---------------- fused fp32->bf16 cast (x + 4 weights) ----------------
struct CastArgs { const float* src[5]; bf16_t* dst[5]; };

__global__ __launch_bounds__(256) void cast_all(CastArgs p) {
  unsigned i = (blockIdx.x * 256u + threadIdx.x) * 4u;
  int seg; unsigned off;
  if (i < 4194304u) { seg = 0; off = i; }
  else { unsigned r = i - 4194304u; seg = 1 + (int)(r >> 20); off = r & 1048575u; }
  const float4 v = *(const float4*)(p.src[seg] + off);
  bf16x4 o = { (bf16_t)v.x, (bf16_t)v.y, (bf16_t)v.z, (bf16_t)v.w };
  *(bf16x4*)(p.dst[seg] + off) = o;
}

// ---------------- 128x128 bf16 GEMM tile, C = A @ W^T ----------------
__device__ __forceinline__ void gemm_tile_128(
    const bf16_t* __restrict__ A, const bf16_t* __restrict__ W,
    bf16_t* Als, bf16_t* Bls, int brow, int bcol, f32x4 acc[4][4])
{
  const int tid = threadIdx.x;
  const int l = tid & 63, w = tid >> 6;
  const int wr = (w >> 1) * 64, wc = (w & 1) * 64;
  const int srow = l >> 2;
  const int scol = ((l & 3) ^ ((l >> 3) & 3)) * 8;
  const int c0 = w * 2;
  const int lh = l >> 4, r15 = l & 15;

  for (int k0 = 0; k0 < D_MODEL; k0 += 32) {
#pragma unroll
    for (int i = 0; i < 2; ++i) {
      int c = c0 + i;
      gload_lds16(A + (size_t)(brow + c * 16 + srow) * D_MODEL + k0 + scol, Als + c * 512);
      gload_lds16(W + (size_t)(bcol + c * 16 + srow) * D_MODEL + k0 + scol, Bls + c * 512);
    }
    asm volatile("s_waitcnt vmcnt(0)" ::: "memory");
    __syncthreads();

    bf16x8 af[4], bfr[4];
#pragma unroll
    for (int mi = 0; mi < 4; ++mi) {
      int rr = wr + mi * 16 + r15;
      int s = lh ^ ((rr >> 1) & 3);
      af[mi] = *(const bf16x8*)(Als + rr * 32 + s * 8);
    }
#pragma unroll
    for (int ni = 0; ni < 4; ++ni) {
      int rr = wc + ni * 16 + r15;
      int s = lh ^ ((rr >> 1) & 3);
      bfr[ni] = *(const bf16x8*)(Bls + rr * 32 + s * 8);
    }
#pragma unroll
    for (int mi = 0; mi < 4; ++mi)
#pragma unroll
      for (int ni = 0; ni < 4; ++ni)
        acc[mi][ni] = __builtin_amdgcn_mfma_f32_16x16x32_bf16(af[mi], bfr[ni], acc[mi][ni], 0, 0, 0);
    __syncthreads();
  }
}

// ---------------- QKV projection: grid (32, 8, 3) ----------------
// z==2 (V) writes TRANSPOSED: vt[b][dcol][t]
struct QKVArgs {
  const bf16_t* A;
  const bf16_t* W[3];
  const float* bias[3];
  bf16_t* out[3];   // out[2] = V^T base
};

__global__ __launch_bounds__(256) void qkv_gemm(QKVArgs p) {
  __shared__ bf16_t Als[128 * 32], Bls[128 * 32];
  f32x4 acc[4][4];
  f32x4 zero = {0.f, 0.f, 0.f, 0.f};
#pragma unroll
  for (int i = 0; i < 4; ++i)
#pragma unroll
    for (int j = 0; j < 4; ++j) acc[i][j] = zero;

  const int z = blockIdx.z;
  const int brow = blockIdx.x * 128, bcol = blockIdx.y * 128;
  gemm_tile_128(p.A, p.W[z], Als, Bls, brow, bcol, acc);

  const int tid = threadIdx.x, l = tid & 63, w = tid >> 6;
  const int wr = (w >> 1) * 64, wc = (w & 1) * 64, lh = l >> 4, r15 = l & 15;
  const float* bias = p.bias[z];
  bf16_t* O = p.out[z];

  if (z == 2) {
#pragma unroll
    for (int ni = 0; ni < 4; ++ni) {
      int col = bcol + wc + ni * 16 + r15;
      float bz = bias[col];
#pragma unroll
      for (int mi = 0; mi < 4; ++mi) {
        int row0 = brow + wr + mi * 16 + lh * 4;
        int bb = row0 >> 11, t0 = row0 & 2047;
        bf16x4 pk;
#pragma unroll
        for (int j = 0; j < 4; ++j) pk[j] = (bf16_t)(acc[mi][ni][j] + bz);
        *(bf16x4*)(O + (size_t)bb * (D_MODEL * T_SEQ) + (size_t)col * T_SEQ + t0) = pk;
      }
    }
  } else {
#pragma unroll
    for (int ni = 0; ni < 4; ++ni) {
      int col = bcol + wc + ni * 16 + r15;
      float bz = bias[col];
#pragma unroll
      for (int mi = 0; mi < 4; ++mi) {
        int row0 = brow + wr + mi * 16 + lh * 4;
#pragma unroll
        for (int j = 0; j < 4; ++j)
          O[(size_t)(row0 + j) * D_MODEL + col] = (bf16_t)(acc[mi][ni][j] + bz);
      }
    }
  }
}

// ---------------- output projection: fp32 epilogue ----------------
__global__ __launch_bounds__(256) void out_gemm(
    const bf16_t* __restrict__ A, const bf16_t* __restrict__ W,
    const float* __restrict__ bias, float* __restrict__ O)
{
  __shared__ bf16_t Als[128 * 32], Bls[128 * 32];
  f32x4 acc[4][4];
  f32x4 zero = {0.f, 0.f, 0.f, 0.f};
#pragma unroll
  for (int i = 0; i < 4; ++i)
#pragma unroll
    for (int j = 0; j < 4; ++j) acc[i][j] = zero;

  const int brow = blockIdx.x * 128, bcol = blockIdx.y * 128;
  gemm_tile_128(A, W, Als, Bls, brow, bcol, acc);

  const int tid = threadIdx.x, l = tid & 63, w = tid >> 6;
  const int wr = (w >> 1) * 64, wc = (w & 1) * 64, lh = l >> 4, r15 = l & 15;
#pragma unroll
  for (int ni = 0; ni < 4; ++ni) {
    int col = bcol + wc + ni * 16 + r15;
    float bz = bias[col];
#pragma unroll
    for (int mi = 0; mi < 4; ++mi) {
      int row0 = brow + wr + mi * 16 + lh * 4;
#pragma unroll
      for (int j = 0; j < 4; ++j)
        O[(size_t)(row0 + j) * D_MODEL + col] = acc[mi][ni][j] + bz;
    }
  }
}

// ---------------- causal flash attention ----------------
// Q,K row-major [B*T][1024]; Vt transposed [B][1024][2048]; O bf16 [B*T][1024]
// Folded-triangle blocks: each block does q-tiles {pair, 31-pair} (64 rows each)
// = exactly 33 kv-tile iterations for every block. 4 waves x 16 q-rows.
__device__ __forceinline__ void stage_kv(const bf16_t* Kg, const bf16_t* Vg,
                                         bf16_t* Kd, bf16_t* Vd, int kv0, int w, int l) {
#pragma unroll
  for (int i = 0; i < 2; ++i) {
    int c = w * 2 + i;
    int rr = c * 8 + (l >> 3);
    int gcol = ((l & 7) ^ ((l >> 3) & 7)) * 8;
    gload_lds16(Kg + (size_t)(kv0 + rr) * D_MODEL + gcol, Kd + c * 512);
    gload_lds16(Vg + (size_t)rr * T_SEQ + kv0 + gcol, Vd + c * 512);
  }
}

__global__ __launch_bounds__(256) void flash_attn(
    const bf16_t* __restrict__ Qm, const bf16_t* __restrict__ Km,
    const bf16_t* __restrict__ Vtg, bf16_t* __restrict__ Om)
{
  __shared__ bf16_t Kls[2][64 * 64];
  __shared__ bf16_t Vls[2][64 * 64];
  __shared__ bf16_t Pls[4][16 * 64];

  const int tid = threadIdx.x, l = tid & 63, w = tid >> 6;
  const int lh = l >> 4, r15 = l & 15;

  // XCD-clustered: all 16 pair-blocks of a head share the XCD (K/V L2-resident)
  const int lid = blockIdx.x;
  const int xcd = lid & 7;
  const int idx = lid >> 3;            // 0..63
  const int pair = idx & 15;           // 0..15
  const int bh = xcd + 8 * (idx >> 4); // bh ≡ xcd (mod 8)
  const int b = bh >> 4, h = bh & 15;
  const int qtA = pair, qtB = 31 - pair;

  const size_t baseQ = (size_t)b * T_SEQ * D_MODEL + h * 64;
  const size_t baseVt = (size_t)b * (D_MODEL * T_SEQ) + (size_t)(h * 64) * T_SEQ;
  const bf16_t* Kg = Km + baseQ;
  const bf16_t* Vg = Vtg + baseVt;

  int qw = qtA * 64 + w * 16;

  bf16x8 qf[2];
  {
    const bf16_t* qp = Qm + baseQ + (size_t)(qw + r15) * D_MODEL + lh * 8;
    qf[0] = *(const bf16x8*)(qp);
    qf[1] = *(const bf16x8*)(qp + 32);
  }

  float l_r[4] = {0.f, 0.f, 0.f, 0.f};
  f32x4 o_acc[4];
  const f32x4 zero = {0.f, 0.f, 0.f, 0.f};
#pragma unroll
  for (int n = 0; n < 4; ++n) o_acc[n] = zero;

  bf16_t* P = &Pls[w][0];
  const int NT = 33;
  const float SCL = 0.18033688011112042f;  // 0.125 * log2(e)

  stage_kv(Kg, Vg, Kls[0], Vls[0], 0, w, l);

  for (int t = 0; t < NT; ++t) {
    const int buf = t & 1;
    if (t + 1 < NT) {
      const int nt = t + 1;
      const int nkv0 = (nt <= qtA) ? nt * 64 : (nt - qtA - 1) * 64;
      stage_kv(Kg, Vg, Kls[buf ^ 1], Vls[buf ^ 1], nkv0, w, l);
      WAITVM(4);
    } else {
      WAITVM(0);
    }
    __builtin_amdgcn_s_barrier();

    const int kv0 = (t <= qtA) ? t * 64 : (t - qtA - 1) * 64;
    const bool diag = (t == qtA) || (t == NT - 1);
    const bf16_t* Kb = Kls[buf];
    const bf16_t* Vb = Vls[buf];

    // ---- S = Q K^T ----
    f32x4 sf[4];
    __builtin_amdgcn_s_setprio(1);
#pragma unroll
    for (int n = 0; n < 4; ++n) {
      const int kvc = n * 16 + r15;
      const int sw = kvc & 7;
      bf16x8 kf0 = *(const bf16x8*)(Kb + kvc * 64 + ((lh ^ sw) * 8));
      bf16x8 kf1 = *(const bf16x8*)(Kb + kvc * 64 + (((4 + lh) ^ sw) * 8));
      f32x4 a = zero;
      a = __builtin_amdgcn_mfma_f32_16x16x32_bf16(qf[0], kf0, a, 0, 0, 0);
      a = __builtin_amdgcn_mfma_f32_16x16x32_bf16(qf[1], kf1, a, 0, 0, 0);
      sf[n] = a;
    }
    __builtin_amdgcn_s_setprio(0);

    // ---- p = exp2(s*scl), mask only on diagonal tiles, pack P ----
    if (diag) {
#pragma unroll
      for (int n = 0; n < 4; ++n) {
        const int kvcol = kv0 + n * 16 + r15;
        const int slot = (n * 16 + r15) >> 3;
#pragma unroll
        for (int j = 0; j < 4; ++j) {
          const int qrow = qw + lh * 4 + j;
          float p = exp2f(sf[n][j] * SCL);
          if (kvcol > qrow) p = 0.f;
          l_r[j] += p;
          const int q7 = (lh * 4 + j) & 7;
          P[(lh * 4 + j) * 64 + ((slot ^ q7) * 8) + (r15 & 7)] = (bf16_t)p;
        }
      }
    } else {
#pragma unroll
      for (int n = 0; n < 4; ++n) {
        const int slot = (n * 16 + r15) >> 3;
#pragma unroll
        for (int j = 0; j < 4; ++j) {
          float p = exp2f(sf[n][j] * SCL);
          l_r[j] += p;
          const int q7 = (lh * 4 + j) & 7;
          P[(lh * 4 + j) * 64 + ((slot ^ q7) * 8) + (r15 & 7)] = (bf16_t)p;
        }
      }
    }

    // ---- O += P V ----
    bf16x8 pa0, pa1;
    {
      const int sw = r15 & 7;
      pa0 = *(const bf16x8*)(P + r15 * 64 + ((lh ^ sw) * 8));
      pa1 = *(const bf16x8*)(P + r15 * 64 + (((4 + lh) ^ sw) * 8));
    }
    __builtin_amdgcn_s_setprio(1);
#pragma unroll
    for (int n = 0; n < 4; ++n) {
      const int d = n * 16 + r15;
      const int sw = d & 7;
      bf16x8 vf0 = *(const bf16x8*)(Vb + d * 64 + ((lh ^ sw) * 8));
      bf16x8 vf1 = *(const bf16x8*)(Vb + d * 64 + (((4 + lh) ^ sw) * 8));
      o_acc[n] = __builtin_amdgcn_mfma_f32_16x16x32_bf16(pa0, vf0, o_acc[n], 0, 0, 0);
      o_acc[n] = __builtin_amdgcn_mfma_f32_16x16x32_bf16(pa1, vf1, o_acc[n], 0, 0, 0);
    }
    __builtin_amdgcn_s_setprio(0);

    __builtin_amdgcn_s_barrier();

    if (t == qtA) {
      // epilogue for q-tile A, then switch to B
#pragma unroll
      for (int off = 1; off < 16; off <<= 1)
#pragma unroll
        for (int j = 0; j < 4; ++j)
          l_r[j] += __shfl_xor(l_r[j], off, 64);
      float invl[4];
#pragma unroll
      for (int j = 0; j < 4; ++j) invl[j] = 1.f / l_r[j];
#pragma unroll
      for (int n = 0; n < 4; ++n) {
        int col = h * 64 + n * 16 + r15;
#pragma unroll
        for (int j = 0; j < 4; ++j) {
          int row = b * T_SEQ + qw + lh * 4 + j;
          Om[(size_t)row * D_MODEL + col] = (bf16_t)(o_acc[n][j] * invl[j]);
        }
      }
      qw = qtB * 64 + w * 16;
      const bf16_t* qp = Qm + baseQ + (size_t)(qw + r15) * D_MODEL + lh * 8;
      qf[0] = *(const bf16x8*)(qp);
      qf[1] = *(const bf16x8*)(qp + 32);
#pragma unroll
      for (int j = 0; j < 4; ++j) l_r[j] = 0.f;
#pragma unroll
      for (int n = 0; n < 4; ++n) o_acc[n] = zero;
    }
  }

  // epilogue for q-tile B
#pragma unroll
  for (int off = 1; off < 16; off <<= 1)
#pragma unroll
    for (int j = 0; j < 4; ++j)
      l_r[j] += __shfl_xor(l_r[j], off, 64);
  float invl[4];
#pragma unroll
  for (int j = 0; j < 4; ++j) invl[j] = 1.f / l_r[j];
#pragma unroll
  for (int n = 0; n < 4; ++n) {
    int col = h * 64 + n * 16 + r15;
#pragma unroll
    for (int j = 0; j < 4; ++j) {
      int row = b * T_SEQ + qw + lh * 4 + j;
      Om[(size_t)row * D_MODEL + col] = (bf16_t)(o_acc[n][j] * invl[j]);
    }
  }
}

// ---------------- host launch ----------------
extern "C" void kernel_launch(void* const* d_in, const int* in_sizes, int n_in,
                              void* d_out, int out_size, void* d_ws, size_t ws_size,
                              hipStream_t stream) {
  const float* x  = (const float*)d_in[0];
  const float* wq = (const float*)d_in[1];
  const float* bq = (const float*)d_in[2];
  const float* wk = (const float*)d_in[3];
  const float* bk = (const float*)d_in[4];
  const float* wv = (const float*)d_in[5];
  const float* bv = (const float*)d_in[6];
  const float* wo = (const float*)d_in[7];
  const float* bo = (const float*)d_in[8];

  char* ws = (char*)d_ws;
  const size_t MB = 1024 * 1024;
  bf16_t* xb  = (bf16_t*)(ws);
  bf16_t* wqb = (bf16_t*)(ws + 8 * MB);
  bf16_t* wkb = (bf16_t*)(ws + 10 * MB);
  bf16_t* wvb = (bf16_t*)(ws + 12 * MB);
  bf16_t* wob = (bf16_t*)(ws + 14 * MB);
  bf16_t* qb  = (bf16_t*)(ws + 16 * MB);
  bf16_t* kb  = (bf16_t*)(ws + 24 * MB);
  bf16_t* vtb = (bf16_t*)(ws + 32 * MB);  // V^T [B][1024][2048]
  bf16_t* ob  = (bf16_t*)(ws + 40 * MB);

  CastArgs ca;
  ca.src[0] = x;  ca.dst[0] = xb;
  ca.src[1] = wq; ca.dst[1] = wqb;
  ca.src[2] = wk; ca.dst[2] = wkb;
  ca.src[3] = wv; ca.dst[3] = wvb;
  ca.src[4] = wo; ca.dst[4] = wob;
  cast_all<<<8192, 256, 0, stream>>>(ca);

  QKVArgs qa;
  qa.A = xb;
  qa.W[0] = wqb; qa.W[1] = wkb; qa.W[2] = wvb;
  qa.bias[0] = bq; qa.bias[1] = bk; qa.bias[2] = bv;
  qa.out[0] = qb; qa.out[1] = kb; qa.out[2] = vtb;
  qkv_gemm<<<dim3(32, 8, 3), 256, 0, stream>>>(qa);

  flash_attn<<<512, 256, 0, stream>>>(qb, kb, vtb, ob);

  out_gemm<<<dim3(32, 8), 256, 0, stream>>>(ob, wob, bo, (float*)d_out);
}